// Round 8
// baseline (160.310 us; speedup 1.0000x reference)
//
#include <hip/hip_runtime.h>
#include <hip/hip_bf16.h>

typedef __bf16 bf16x8 __attribute__((ext_vector_type(8)));
typedef float f32x16 __attribute__((ext_vector_type(16)));
typedef unsigned int u32;
typedef unsigned short u16;

// ws layout (bytes):
//   [0,       524288)  WtP2  : bf16 W_enc frag pack [cg=4][nt=4][ks=32][lane=64][e=8]
//   [524288,  655360)  bias2p: f32 [64][512]
//   [655360, 1703936)  plog  : f32 [4][65536] partial logits per col-group
#define WS_WT   0
#define WS_BIAS 524288
#define WS_PLOG 655360

__device__ __forceinline__ u16 f2bf(float f) {
    __bf16 h = (__bf16)f;
    return __builtin_bit_cast(u16, h);
}

__device__ __forceinline__ void gload_lds16(const void* g, void* l) {
    __builtin_amdgcn_global_load_lds(
        (const __attribute__((address_space(1))) u32*)g,
        (__attribute__((address_space(3))) u32*)l, 16, 0, 0);
}

__device__ __forceinline__ bf16x8 cvt8(float4 a, float4 b) {
    bf16x8 r;
    r[0] = (__bf16)a.x; r[1] = (__bf16)a.y; r[2] = (__bf16)a.z; r[3] = (__bf16)a.w;
    r[4] = (__bf16)b.x; r[5] = (__bf16)b.y; r[6] = (__bf16)b.z; r[7] = (__bf16)b.w;
    return r;
}

// K0a: pack W_enc into mfma_32x32x16 B-frag layout, lane-contiguous.
// unit u (16B): l=u&63, ks=(u>>6)&31, nt=(u>>11)&3, cg=u>>13
// value e: W[(ks*16 + (l>>5)*8 + e)*512 + cg*128 + nt*32 + (l&31)]
__global__ void k_wt(const float* __restrict__ W, u16* __restrict__ WtP2) {
    int u = blockIdx.x * 256 + threadIdx.x;     // 32768 units
    int l = u & 63, ks = (u >> 6) & 31, nt = (u >> 11) & 3, cg = u >> 13;
    int n = cg * 128 + nt * 32 + (l & 31);
    int k0 = ks * 16 + (l >> 5) * 8;
    u16 o[8];
    #pragma unroll
    for (int e = 0; e < 8; ++e)
        o[e] = f2bf(W[(k0 + e) * 512 + n]);
    *(uint4*)(WtP2 + (size_t)u * 8) = *(const uint4*)o;
}

// K0b: bias2p[b][n] = dec[b]·W_dec[:,n] + b_dec[n] + b_enc[n]
__global__ void k_bias2(const float* __restrict__ dec, const float* __restrict__ Wd,
                        const float* __restrict__ b_dec, const float* __restrict__ b_enc,
                        float* __restrict__ bias2p) {
    int blk = blockIdx.x;
    int b = blk >> 2, nc = blk & 3;
    int t = threadIdx.x;
    __shared__ float sdec[512];
    __shared__ float red[256];
    for (int k = t; k < 512; k += 256) sdec[k] = dec[b * 512 + k];
    __syncthreads();
    int n = nc * 128 + (t & 127);
    int kh = t >> 7;
    float acc = 0.f;
    int k0 = kh * 256;
    #pragma unroll 4
    for (int k = k0; k < k0 + 256; ++k)
        acc += sdec[k] * Wd[k * 512 + n];
    red[t] = acc;
    __syncthreads();
    if (t < 128) {
        int nn = nc * 128 + t;
        bias2p[b * 512 + nn] = red[t] + red[t + 128] + b_dec[nn] + b_enc[nn];
    }
}

// K1: fused enc@W_enc(+bias,relu,·Wf) partials. BARRIER-FREE main loop.
// 512 blocks x 512 thr: cg = blk&3 (128 cols), rb = blk>>2 (512 rows).
// B-quarter resident in LDS (128 KB, loaded once). Wave = 64 rows x 128 cols,
// mfma_32x32x16, A prefetched 4-deep from global (static ring).
__global__ __launch_bounds__(512, 2) void k_logits(
        const float* __restrict__ enc, const u16* __restrict__ WtP2,
        const float* __restrict__ bias2p, const float* __restrict__ Wf,
        float* __restrict__ plog) {
    __shared__ __align__(16) char ldsB[131072];

    int t = threadIdx.x;
    int lane = t & 63;
    int w = t >> 6;                 // wave 0..7
    int blk = blockIdx.x;           // 512
    int cg = blk & 3;
    int rb = blk >> 2;              // 128 row-blocks of 512 rows
    int r0 = rb * 512 + w * 64;     // this wave's 64 rows
    int bidx = r0 >> 10;            // batch

    // stage B-quarter (128 KB) once: fully coalesced, linear LDS
    {
        const char* bsrc = (const char*)WtP2 + (size_t)cg * 131072 + w * 16384 + lane * 16;
        char* bdst = ldsB + w * 16384;
        #pragma unroll
        for (int j = 0; j < 16; ++j)
            gload_lds16(bsrc + j * 1024, bdst + j * 1024);
    }

    // A prefetch ring, depth 4 (static indices only)
    const float* ap0 = enc + (size_t)(r0 + (lane & 31)) * 512 + (lane >> 5) * 8;
    const float* ap1 = ap0 + 32 * 512;
    float4 a0lo[4], a0hi[4], a1lo[4], a1hi[4];
    #pragma unroll
    for (int j = 0; j < 4; ++j) {
        a0lo[j] = *(const float4*)(ap0 + j * 16);
        a0hi[j] = *(const float4*)(ap0 + j * 16 + 4);
        a1lo[j] = *(const float4*)(ap1 + j * 16);
        a1hi[j] = *(const float4*)(ap1 + j * 16 + 4);
    }

    __syncthreads();                // B resident; no more barriers

    f32x16 acc0[4], acc1[4];
    #pragma unroll
    for (int nt = 0; nt < 4; ++nt) { acc0[nt] = (f32x16){}; acc1[nt] = (f32x16){}; }

    for (int ks4 = 0; ks4 < 8; ++ks4) {
        #pragma unroll
        for (int j = 0; j < 4; ++j) {
            int ks = ks4 * 4 + j;
            bf16x8 A0 = cvt8(a0lo[j], a0hi[j]);
            bf16x8 A1 = cvt8(a1lo[j], a1hi[j]);
            if (ks < 28) {          // prefetch step ks+4 into slot j
                a0lo[j] = *(const float4*)(ap0 + (ks + 4) * 16);
                a0hi[j] = *(const float4*)(ap0 + (ks + 4) * 16 + 4);
                a1lo[j] = *(const float4*)(ap1 + (ks + 4) * 16);
                a1hi[j] = *(const float4*)(ap1 + (ks + 4) * 16 + 4);
            }
            #pragma unroll
            for (int nt = 0; nt < 4; ++nt) {
                uint4 braw = *(const uint4*)(ldsB + (size_t)(nt * 32 + ks) * 1024 + lane * 16);
                bf16x8 Bf = __builtin_bit_cast(bf16x8, braw);
                acc0[nt] = __builtin_amdgcn_mfma_f32_32x32x16_bf16(A0, Bf, acc0[nt], 0, 0, 0);
                acc1[nt] = __builtin_amdgcn_mfma_f32_32x32x16_bf16(A1, Bf, acc1[nt], 0, 0, 0);
            }
        }
    }

    // epilogue: relu(acc+bias)·Wf, reduce over this block's 128 cols
    float p0[16], p1[16];
    #pragma unroll
    for (int r = 0; r < 16; ++r) { p0[r] = 0.f; p1[r] = 0.f; }
    #pragma unroll
    for (int nt = 0; nt < 4; ++nt) {
        int col = cg * 128 + nt * 32 + (lane & 31);
        float bias = bias2p[bidx * 512 + col];
        float wfv = Wf[col];
        #pragma unroll
        for (int r = 0; r < 16; ++r) {
            float v0 = acc0[nt][r] + bias; v0 = v0 > 0.f ? v0 : 0.f; p0[r] += v0 * wfv;
            float v1 = acc1[nt][r] + bias; v1 = v1 > 0.f ? v1 : 0.f; p1[r] += v1 * wfv;
        }
    }
    int hi = lane >> 5;
    #pragma unroll
    for (int r = 0; r < 16; ++r) {
        float v = p0[r];
        v += __shfl_xor(v, 1, 64);
        v += __shfl_xor(v, 2, 64);
        v += __shfl_xor(v, 4, 64);
        v += __shfl_xor(v, 8, 64);
        v += __shfl_xor(v, 16, 64);
        float u = p1[r];
        u += __shfl_xor(u, 1, 64);
        u += __shfl_xor(u, 2, 64);
        u += __shfl_xor(u, 4, 64);
        u += __shfl_xor(u, 8, 64);
        u += __shfl_xor(u, 16, 64);
        if ((lane & 31) == 0) {
            int row = (r & 3) + 8 * (r >> 2) + 4 * hi;
            plog[(size_t)cg * 65536 + r0 + row] = v;
            plog[(size_t)cg * 65536 + r0 + 32 + row] = u;
        }
    }
}

// K2: sum 4 plog partials -> softmax over L; also zero-inits out[0..32768)
__global__ void k_softmax(const float* __restrict__ plog, float* __restrict__ out,
                          float* __restrict__ alpha) {
    int b = blockIdx.x;
    int t = threadIdx.x;
    if (t < 128)
        *(float4*)(out + b * 512 + t * 4) = (float4){0.f, 0.f, 0.f, 0.f};
    __shared__ float red[256];
    float4 v0 = *(const float4*)(plog + b * 1024 + t * 4);
    float4 v1 = *(const float4*)(plog + 65536 + b * 1024 + t * 4);
    float4 v2 = *(const float4*)(plog + 131072 + b * 1024 + t * 4);
    float4 v3 = *(const float4*)(plog + 196608 + b * 1024 + t * 4);
    float4 v;
    v.x = v0.x + v1.x + v2.x + v3.x;
    v.y = v0.y + v1.y + v2.y + v3.y;
    v.z = v0.z + v1.z + v2.z + v3.z;
    v.w = v0.w + v1.w + v2.w + v3.w;
    float mx = fmaxf(fmaxf(v.x, v.y), fmaxf(v.z, v.w));
    red[t] = mx;
    __syncthreads();
    for (int s = 128; s > 0; s >>= 1) {
        if (t < s) red[t] = fmaxf(red[t], red[t + s]);
        __syncthreads();
    }
    mx = red[0];
    __syncthreads();
    float4 e;
    e.x = expf(v.x - mx); e.y = expf(v.y - mx);
    e.z = expf(v.z - mx); e.w = expf(v.w - mx);
    red[t] = e.x + e.y + e.z + e.w;
    __syncthreads();
    for (int s = 128; s > 0; s >>= 1) {
        if (t < s) red[t] += red[t + s];
        __syncthreads();
    }
    float inv = 1.0f / red[0];
    float4 o;
    o.x = e.x * inv; o.y = e.y * inv; o.z = e.z * inv; o.w = e.w * inv;
    ((float4*)(alpha + b * 1024))[t] = o;
}

// K3: weighted sums over l-chunks of 128, atomicAdd into out
__global__ void k_wsum_part(const float* __restrict__ enc, const float* __restrict__ alpha,
                            float* __restrict__ out) {
    int blk = blockIdx.x;           // 512 blocks: b = blk>>3, chunk c = blk&7
    int b = blk >> 3, c = blk & 7;
    int t = threadIdx.x;
    int col = (t & 127) * 4;
    int lh = t >> 7;
    const float* ep = enc + (size_t)(b * 1024 + c * 128) * 512;
    const float* al = alpha + b * 1024 + c * 128;
    float4 s = {0.f, 0.f, 0.f, 0.f};
    #pragma unroll 4
    for (int i = 0; i < 64; ++i) {
        int l = i * 2 + lh;
        float a = al[l];
        float4 e = *(const float4*)(ep + (size_t)l * 512 + col);
        s.x += e.x * a; s.y += e.y * a; s.z += e.z * a; s.w += e.w * a;
    }
    __shared__ float red[2][512];
    *(float4*)&red[lh][col] = s;
    __syncthreads();
    if (t < 128) {
        float4 a0 = *(const float4*)&red[0][t * 4];
        float4 a1 = *(const float4*)&red[1][t * 4];
        float* op = out + b * 512 + t * 4;
        atomicAdd(op + 0, a0.x + a1.x);
        atomicAdd(op + 1, a0.y + a1.y);
        atomicAdd(op + 2, a0.z + a1.z);
        atomicAdd(op + 3, a0.w + a1.w);
    }
}

extern "C" void kernel_launch(void* const* d_in, const int* in_sizes, int n_in,
                              void* d_out, int out_size, void* d_ws, size_t ws_size,
                              hipStream_t stream) {
    const float* enc    = (const float*)d_in[0];  // [64,1024,512]
    const float* dec    = (const float*)d_in[1];  // [64,512]
    const float* W_enc  = (const float*)d_in[2];  // [512,512]
    const float* b_enc  = (const float*)d_in[3];  // [512]
    const float* W_dec  = (const float*)d_in[4];  // [512,512]
    const float* b_dec  = (const float*)d_in[5];  // [512]
    const float* W_full = (const float*)d_in[6];  // [512]
    // d_in[7] = b_full: unused (softmax is shift-invariant)

    float* out = (float*)d_out;                   // [0,32768) weighted enc; [32768,98304) alpha
    char* ws = (char*)d_ws;
    u16* WtP2     = (u16*)(ws + WS_WT);
    float* bias2p = (float*)(ws + WS_BIAS);
    float* plog   = (float*)(ws + WS_PLOG);
    float* alpha  = out + 32768;

    hipLaunchKernelGGL(k_wt,        dim3(128), dim3(256), 0, stream, W_enc, WtP2);
    hipLaunchKernelGGL(k_bias2,     dim3(256), dim3(256), 0, stream, dec, W_dec, b_dec, b_enc, bias2p);
    hipLaunchKernelGGL(k_logits,    dim3(512), dim3(512), 0, stream, enc, WtP2, bias2p, W_full, plog);
    hipLaunchKernelGGL(k_softmax,   dim3(64),  dim3(256), 0, stream, plog, out, alpha);
    hipLaunchKernelGGL(k_wsum_part, dim3(512), dim3(256), 0, stream, enc, alpha, out);
}

// Round 10
// 106.587 us; speedup vs baseline: 1.5040x; 1.5040x over previous
//
#include <hip/hip_runtime.h>
#include <hip/hip_bf16.h>

typedef __bf16 bf16x8 __attribute__((ext_vector_type(8)));
typedef float f32x16 __attribute__((ext_vector_type(16)));
typedef unsigned int u32;
typedef unsigned short u16;

// ws layout (bytes):
//   [0,       524288)  WtP   : bf16 W_enc pack [p=16][ks=32][lane=64][e=8]
//   [524288,  655360)  bias2p: f32 [64][512]
//   [655360,  917504)  logits: f32 [65536]
#define WS_WT     0
#define WS_BIAS   524288
#define WS_LOGITS 655360

__device__ __forceinline__ u16 f2bf(float f) {
    __bf16 h = (__bf16)f;
    return __builtin_bit_cast(u16, h);
}

__device__ __forceinline__ void gload_lds16(const void* g, void* l) {
    __builtin_amdgcn_global_load_lds(
        (const __attribute__((address_space(1))) u32*)g,
        (__attribute__((address_space(3))) u32*)l, 16, 0, 0);
}

__device__ __forceinline__ bf16x8 cvt8(float4 a, float4 b) {
    bf16x8 r;
    r[0] = (__bf16)a.x; r[1] = (__bf16)a.y; r[2] = (__bf16)a.z; r[3] = (__bf16)a.w;
    r[4] = (__bf16)b.x; r[5] = (__bf16)b.y; r[6] = (__bf16)b.z; r[7] = (__bf16)b.w;
    return r;
}

// K0a: pack W_enc. unit u (16B): l=u&63, ks=(u>>6)&31, p=u>>11.
// elem e: W[k][n], n = p*32 + (l&31), k = ks*16 + (l>>5)*8 + e
__global__ void k_wt(const float* __restrict__ W, u16* __restrict__ WtP) {
    int u = blockIdx.x * 256 + threadIdx.x;     // 32768 units
    int l = u & 63, ks = (u >> 6) & 31, p = u >> 11;
    int n = p * 32 + (l & 31);
    int k0 = ks * 16 + (l >> 5) * 8;
    u16 o[8];
    #pragma unroll
    for (int e = 0; e < 8; ++e)
        o[e] = f2bf(W[(k0 + e) * 512 + n]);
    *(uint4*)(WtP + (size_t)u * 8) = *(const uint4*)o;
}

// K0b: bias2p = dec·W_dec + b_dec + b_enc; blocks 0..63 also zero out[0..32768)
__global__ void k_bias2(const float* __restrict__ dec, const float* __restrict__ Wd,
                        const float* __restrict__ b_dec, const float* __restrict__ b_enc,
                        float* __restrict__ bias2p, float* __restrict__ out0) {
    int blk = blockIdx.x;
    int b = blk >> 2, nc = blk & 3;
    int t = threadIdx.x;
    if (blk < 64) {
        out0[blk * 512 + t * 2] = 0.f;
        out0[blk * 512 + t * 2 + 1] = 0.f;
    }
    __shared__ float sdec[512];
    __shared__ float red[256];
    for (int k = t; k < 512; k += 256) sdec[k] = dec[b * 512 + k];
    __syncthreads();
    int n = nc * 128 + (t & 127);
    int kh = t >> 7;
    float acc = 0.f;
    int k0 = kh * 256;
    #pragma unroll 4
    for (int k = k0; k < k0 + 256; ++k)
        acc += sdec[k] * Wd[k * 512 + n];
    red[t] = acc;
    __syncthreads();
    if (t < 128) {
        int nn = nc * 128 + t;
        bias2p[b * 512 + nn] = red[t] + red[t + 128] + b_dec[nn] + b_enc[nn];
    }
}

// K1: fused enc@W_enc + bias -> relu -> ·Wf  =>  logits [B*L]
// 512 blocks x 256 thr (4 waves), 2 blocks/CU (64KB LDS). Block = 128 rows.
// Wave = 32 rows, full-K A resident (32 bf16x8 = 128 VGPR, pinned).
// Prologue: A via coalesced gload_lds rounds (HBM-BW-bound).
// Main: B phased through dbuf LDS (L2-hot), conflict-free 1KB frag reads.
__global__ __launch_bounds__(256, 2) void k_logits(
        const float* __restrict__ enc, const u16* __restrict__ WtP,
        const float* __restrict__ bias2p, const float* __restrict__ Wf,
        float* __restrict__ logits) {
    __shared__ __align__(16) char ldsA[32768];   // A stage: 16 rows fp32
    __shared__ __align__(16) char ldsB0[16384];  // B half-phase dbuf
    __shared__ __align__(16) char ldsB1[16384];

    int t = threadIdx.x;
    int lane = t & 63;
    int w = t >> 6;                 // wave 0..3
    int blk = blockIdx.x;           // 512 blocks of 128 rows
    int b = blk >> 3;               // batch
    int cl = lane & 31;
    int hi = lane >> 5;

    // B half: phase p, half h (16KB = frags ks in [h*16, h*16+16))
    #define STAGEB(buf, p_, h_)                                                   \
        {                                                                         \
            const char* s_ = (const char*)WtP + (size_t)(p_) * 32768              \
                             + (h_) * 16384 + t * 16;                             \
            _Pragma("unroll")                                                     \
            for (int j = 0; j < 4; ++j)                                           \
                gload_lds16(s_ + j * 4096, (char*)(buf) + t * 16 + j * 4096);     \
        }
    // A stage s: rows blk*128 + s*16 .. +15, fp32, source XOR-swizzled (c ^ (r&7))
    #define STAGEA(s_)                                                            \
        {                                                                         \
            size_t base_ = ((size_t)blk * 128 + (s_) * 16) * 2048;                \
            _Pragma("unroll")                                                     \
            for (int j = 0; j < 8; ++j) {                                         \
                int u_ = t + j * 256;                                             \
                int r_ = u_ >> 7, c_ = u_ & 127;                                  \
                const char* src_ = (const char*)enc + base_ + (size_t)r_ * 2048   \
                                   + ((size_t)(c_ ^ (r_ & 7)) * 16);              \
                gload_lds16(src_, ldsA + (size_t)u_ * 16);                        \
            }                                                                     \
        }

    // ---- prologue: B(0,h0) + A acquisition (8 rounds of 16 rows) ----
    STAGEB(ldsB0, 0, 0)
    STAGEA(0)

    bf16x8 A[32];
    int rloc = lane & 15;
    int myswz = rloc & 7;
    int parity = (lane >> 4) & 1;   // which stage parity this lane consumes
    for (int s = 0; s < 8; ++s) {
        __syncthreads();            // stage s landed (auto vmcnt drain)
        if ((s >> 1) == w && (s & 1) == parity) {
            #pragma unroll
            for (int f = 0; f < 32; ++f) {
                int c0 = (f * 4 + hi * 2) ^ myswz;
                int c1 = (f * 4 + hi * 2 + 1) ^ myswz;
                float4 lo = *(const float4*)(ldsA + rloc * 2048 + c0 * 16);
                float4 h4 = *(const float4*)(ldsA + rloc * 2048 + c1 * 16);
                A[f] = cvt8(lo, h4);
            }
        }
        __syncthreads();            // reads done before overwrite
        if (s < 7) STAGEA(s + 1)
    }
    #pragma unroll
    for (int f = 0; f < 32; ++f)
        asm volatile("" : "+v"(A[f]));   // pin: no remat of enc loads

    // ---- 16 phases x 32 cols, K-half double-buffered ----
    float pr[16];
    #pragma unroll
    for (int r = 0; r < 16; ++r) pr[r] = 0.f;

    for (int p = 0; p < 16; ++p) {
        __syncthreads();            // ldsB0(p,h0) ready; ldsB1 reads of p-1 done
        STAGEB(ldsB1, p, 1)
        f32x16 acc0 = {};
        #pragma unroll
        for (int i = 0; i < 16; ++i) {
            uint4 braw = *(const uint4*)(ldsB0 + i * 1024 + lane * 16);
            acc0 = __builtin_amdgcn_mfma_f32_32x32x16_bf16(
                A[i], __builtin_bit_cast(bf16x8, braw), acc0, 0, 0, 0);
        }
        __syncthreads();            // ldsB1 ready; ldsB0 reads done
        if (p < 15) STAGEB(ldsB0, p + 1, 0)
        f32x16 acc1 = {};
        #pragma unroll
        for (int i = 0; i < 16; ++i) {
            uint4 braw = *(const uint4*)(ldsB1 + i * 1024 + lane * 16);
            acc1 = __builtin_amdgcn_mfma_f32_32x32x16_bf16(
                A[16 + i], __builtin_bit_cast(bf16x8, braw), acc1, 0, 0, 0);
        }
        int col = p * 32 + cl;
        float bias = bias2p[b * 512 + col];
        float wfv = Wf[col];
        #pragma unroll
        for (int r = 0; r < 16; ++r) {
            float v = acc0[r] + acc1[r] + bias;
            v = v > 0.f ? v : 0.f;
            pr[r] += v * wfv;
        }
    }

    // reduce over the 32 col-lanes; lane cl==0 (both hi) writes 32 rows
    #pragma unroll
    for (int r = 0; r < 16; ++r) {
        float v = pr[r];
        v += __shfl_xor(v, 1, 64);
        v += __shfl_xor(v, 2, 64);
        v += __shfl_xor(v, 4, 64);
        v += __shfl_xor(v, 8, 64);
        v += __shfl_xor(v, 16, 64);
        if (cl == 0)
            logits[blk * 128 + w * 32 + (r & 3) + 8 * (r >> 2) + 4 * hi] = v;
    }
}

// K2: softmax over L per batch (b_full omitted: softmax is shift-invariant)
__global__ void k_softmax(const float* __restrict__ logits, float* __restrict__ alpha) {
    int b = blockIdx.x;
    int t = threadIdx.x;
    __shared__ float red[256];
    float4 v = ((const float4*)(logits + b * 1024))[t];
    float mx = fmaxf(fmaxf(v.x, v.y), fmaxf(v.z, v.w));
    red[t] = mx;
    __syncthreads();
    for (int s = 128; s > 0; s >>= 1) {
        if (t < s) red[t] = fmaxf(red[t], red[t + s]);
        __syncthreads();
    }
    mx = red[0];
    __syncthreads();
    float4 e;
    e.x = expf(v.x - mx); e.y = expf(v.y - mx);
    e.z = expf(v.z - mx); e.w = expf(v.w - mx);
    red[t] = e.x + e.y + e.z + e.w;
    __syncthreads();
    for (int s = 128; s > 0; s >>= 1) {
        if (t < s) red[t] += red[t + s];
        __syncthreads();
    }
    float inv = 1.0f / red[0];
    float4 o;
    o.x = e.x * inv; o.y = e.y * inv; o.z = e.z * inv; o.w = e.w * inv;
    ((float4*)(alpha + b * 1024))[t] = o;
}

// K3: weighted sums over l-chunks of 128, atomicAdd into out (zeroed by k_bias2)
__global__ void k_wsum_part(const float* __restrict__ enc, const float* __restrict__ alpha,
                            float* __restrict__ out) {
    int blk = blockIdx.x;           // 512 blocks: b = blk>>3, chunk c = blk&7
    int b = blk >> 3, c = blk & 7;
    int t = threadIdx.x;
    int col = (t & 127) * 4;
    int lh = t >> 7;
    const float* ep = enc + (size_t)(b * 1024 + c * 128) * 512;
    const float* al = alpha + b * 1024 + c * 128;
    float4 s = {0.f, 0.f, 0.f, 0.f};
    #pragma unroll 4
    for (int i = 0; i < 64; ++i) {
        int l = i * 2 + lh;
        float a = al[l];
        float4 e = *(const float4*)(ep + (size_t)l * 512 + col);
        s.x += e.x * a; s.y += e.y * a; s.z += e.z * a; s.w += e.w * a;
    }
    __shared__ float red[2][512];
    *(float4*)&red[lh][col] = s;
    __syncthreads();
    if (t < 128) {
        float4 a0 = *(const float4*)&red[0][t * 4];
        float4 a1 = *(const float4*)&red[1][t * 4];
        float* op = out + b * 512 + t * 4;
        atomicAdd(op + 0, a0.x + a1.x);
        atomicAdd(op + 1, a0.y + a1.y);
        atomicAdd(op + 2, a0.z + a1.z);
        atomicAdd(op + 3, a0.w + a1.w);
    }
}

extern "C" void kernel_launch(void* const* d_in, const int* in_sizes, int n_in,
                              void* d_out, int out_size, void* d_ws, size_t ws_size,
                              hipStream_t stream) {
    const float* enc    = (const float*)d_in[0];  // [64,1024,512]
    const float* dec    = (const float*)d_in[1];  // [64,512]
    const float* W_enc  = (const float*)d_in[2];  // [512,512]
    const float* b_enc  = (const float*)d_in[3];  // [512]
    const float* W_dec  = (const float*)d_in[4];  // [512,512]
    const float* b_dec  = (const float*)d_in[5];  // [512]
    const float* W_full = (const float*)d_in[6];  // [512]
    // d_in[7] = b_full: unused (softmax is shift-invariant)

    float* out = (float*)d_out;                   // [0,32768) weighted enc; [32768,98304) alpha
    char* ws = (char*)d_ws;
    u16* WtP      = (u16*)(ws + WS_WT);
    float* bias2p = (float*)(ws + WS_BIAS);
    float* logits = (float*)(ws + WS_LOGITS);
    float* alpha  = out + 32768;

    hipLaunchKernelGGL(k_wt,        dim3(128), dim3(256), 0, stream, W_enc, WtP);
    hipLaunchKernelGGL(k_bias2,     dim3(256), dim3(256), 0, stream,
                       dec, W_dec, b_dec, b_enc, bias2p, out);
    hipLaunchKernelGGL(k_logits,    dim3(512), dim3(256), 0, stream,
                       enc, WtP, bias2p, W_full, logits);
    hipLaunchKernelGGL(k_softmax,   dim3(64),  dim3(256), 0, stream, logits, alpha);
    hipLaunchKernelGGL(k_wsum_part, dim3(512), dim3(256), 0, stream, enc, alpha, out);
}